// Round 6
// baseline (51.989 us; speedup 1.0000x reference)
//
#include <hip/hip_runtime.h>
#include <math.h>

#define Bsz 32
#define Cc  16
#define Hh  64
#define Ww  64
#define HO  62
#define WO  62
#define OD  64
#define ND  144
#define KC  18            // K-steps of BK=64 (8 slots x 8 feats); 18*8 = 144 = ND

using short8 = __attribute__((ext_vector_type(8))) short;
using f32x4  = __attribute__((ext_vector_type(4))) float;
using f32x16 = __attribute__((ext_vector_type(16))) float;
typedef unsigned int u32;
typedef unsigned short ushort;

__device__ __forceinline__ ushort f2bf(float f) {
    union { float f; unsigned u; } v; v.f = f;
    unsigned r = v.u + 0x7fff + ((v.u >> 16) & 1);
    return (ushort)(r >> 16);
}
__device__ __forceinline__ float bf2f(ushort h) {
    union { unsigned u; float f; } v; v.u = ((unsigned)h) << 16; return v.f;
}

__device__ __forceinline__ void gload_lds16(const void* g, void* l) {
    __builtin_amdgcn_global_load_lds((const __attribute__((address_space(1))) u32*)g,
                                     (__attribute__((address_space(3))) u32*)l,
                                     16, 0, 0);
}

__device__ __forceinline__ uint4 feat_pack(float xv) {
    float xi = (xv + 3.0f) * 1.5f;
    float fi = floorf(xi);
    int   ii = (int)fi;
    float u  = xi - fi;
    float u2 = u * u, u3 = u2 * u;
    float P0 = u3 * (1.0f / 6.0f);
    float P1 = (1.0f + 3.0f * u + 3.0f * u2 - 3.0f * u3) * (1.0f / 6.0f);
    float P2 = (4.0f - 6.0f * u2 + 3.0f * u3) * (1.0f / 6.0f);
    float om = 1.0f - u;
    float P3 = om * om * om * (1.0f / 6.0f);
    bool ok = (ii >= 0) && (ii <= 8);
    float bas[6];
    #pragma unroll
    for (int n = 0; n < 6; ++n) {
        int t = ii - n;
        float v = (t == 0) ? P0 : (t == 1) ? P1 : (t == 2) ? P2 : (t == 3) ? P3 : 0.0f;
        bas[n] = ok ? v : 0.0f;
    }
    float s = xv / (1.0f + __expf(-xv));
    ushort sh = f2bf(s);
    ushort sl = f2bf(s - bf2f(sh));
    uint4 pk;
    pk.x = (unsigned)f2bf(bas[0]) | ((unsigned)f2bf(bas[1]) << 16);
    pk.y = (unsigned)f2bf(bas[2]) | ((unsigned)f2bf(bas[3]) << 16);
    pk.z = (unsigned)f2bf(bas[4]) | ((unsigned)f2bf(bas[5]) << 16);
    pk.w = (unsigned)sh | ((unsigned)sl << 16);
    return pk;
}

// ---- kernel 1: per-element packed features into ws (33.5 MB), coalesced ----
__global__ __launch_bounds__(256) void kan_feat(const float* __restrict__ x,
                                                uint4* __restrict__ fg) {
    int base = blockIdx.x * 2048 + threadIdx.x;
    #pragma unroll
    for (int j = 0; j < 8; ++j) {
        int i = base + j * 256;
        fg[i] = feat_pack(x[i]);
    }
}

// ---- kernel 1b: B image [kc][kb(8)][n(64)] x 8 bf16 feats; d = kc*8+kb ----
__global__ __launch_bounds__(256) void kan_prep3(const float* __restrict__ coef,
                                                 const float* __restrict__ sbase,
                                                 const float* __restrict__ ssp,
                                                 ushort* __restrict__ wpb) {
    int g = blockIdx.x * 256 + threadIdx.x;
    if (g >= KC * 8 * 64) return;
    int n = g & 63, d = g >> 6;            // d = kc*8 + kb, 0..143
    float sspv = ssp[d * OD + n];
    ushort sb = f2bf(sbase[d * OD + n]);
    ushort v[8];
    #pragma unroll
    for (int f = 0; f < 6; ++f) v[f] = f2bf(coef[(d * OD + n) * 6 + f] * sspv);
    v[6] = sb; v[7] = sb;
    uint4 pk;
    pk.x = (unsigned)v[0] | ((unsigned)v[1] << 16);
    pk.y = (unsigned)v[2] | ((unsigned)v[3] << 16);
    pk.z = (unsigned)v[4] | ((unsigned)v[5] << 16);
    pk.w = (unsigned)v[6] | ((unsigned)v[7] << 16);
    *(uint4*)&wpb[(size_t)g * 8] = pk;
}

// ---- kernel 2: tiled GEMM, BM=128 px (2 h-rows) x BN=64 x BK=64, dbuf LDS,
//      global_load_lds staging, mfma 32x32x16, 3 blocks/CU ----
__global__ __launch_bounds__(256, 3) void kan_gemm2(const uint4* __restrict__ fg,
                                                    const uint4* __restrict__ wpb,
                                                    float* __restrict__ out) {
    __shared__ uint4 ldsmem[3072];           // 49,152 B: 2 x (A 16KB + B 8KB)
    char* lds = (char*)ldsmem;

    const int tid  = threadIdx.x;
    const int wid  = tid >> 6;
    const int lane = tid & 63;
    const int l31  = lane & 31;
    const int hi   = lane >> 5;
    const int mt   = blockIdx.x;             // 0..30 -> h0 = 2*mt (h0+1 <= 61)
    const int bb   = blockIdx.y;             // batch
    const int h0   = mt * 2;

    auto stage = [&](int kc, int bufsel) {
        char* bufA = lds + bufsel * 24576;
        char* bufB = bufA + 16384;
        #pragma unroll
        for (int q = 0; q < 2; ++q) {
            int s = wid + q * 4;             // K-slot within step (wave-uniform)
            int d = kc * 8 + s;              // input dim, 0..143
            int c   = (d * 57) >> 9;         // d/9
            int rem = d - c * 9;
            int di  = (rem * 11) >> 5;       // rem/3
            int dj  = rem - di * 3;
            int su  = c * 4096 + (h0 + di) * 64 + dj;
            #pragma unroll
            for (int hh = 0; hh < 2; ++hh) {
                const char* src = (const char*)fg +
                    ((size_t)(bb * 65536 + su + hh * 64 + lane) * 16);
                gload_lds16(src, bufA + (s * 128 + hh * 64) * 16);
            }
        }
        #pragma unroll
        for (int q = 0; q < 2; ++q) {
            int kb = wid + q * 4;
            const char* src = (const char*)wpb + ((size_t)(kc * 512 + kb * 64 + lane) * 16);
            gload_lds16(src, bufB + kb * 1024);
        }
    };

    f32x16 acc0, acc1;
    #pragma unroll
    for (int i = 0; i < 16; ++i) { acc0[i] = 0.0f; acc1[i] = 0.0f; }

    stage(0, 0);
    __syncthreads();

    const int m0 = wid * 32 + l31;           // pixel-row within tile, 0..127

    #pragma unroll
    for (int kc = 0; kc < KC; ++kc) {
        const int cur = kc & 1;
        if (kc + 1 < KC) stage(kc + 1, cur ^ 1);
        const ushort* A  = (const ushort*)(lds + cur * 24576);
        const ushort* Bw = (const ushort*)(lds + cur * 24576 + 16384);
        #pragma unroll
        for (int kk = 0; kk < 4; ++kk) {
            const int sl = kk * 2 + hi;      // k-octet selector (lane>>5)
            short8 a  = *(const short8*)(A  + (size_t)(sl * 128 + m0) * 8);
            short8 b0 = *(const short8*)(Bw + (size_t)(sl * 64 + l31) * 8);
            short8 b1 = *(const short8*)(Bw + (size_t)(sl * 64 + 32 + l31) * 8);
            acc0 = __builtin_amdgcn_mfma_f32_32x32x16_bf16(a, b0, acc0, 0, 0, 0);
            acc1 = __builtin_amdgcn_mfma_f32_32x32x16_bf16(a, b1, acc1, 0, 0, 0);
        }
        __syncthreads();
    }

    // epilogue: C scratch [o=64][m stride 130] f32 (33,280 B), then row stores
    float* Csc = (float*)lds;
    #pragma unroll
    for (int r = 0; r < 16; ++r) {
        int ml = (r & 3) + ((r >> 2) << 3) + (hi << 2);   // C row = pixel-local
        Csc[(size_t)l31 * 130 + wid * 32 + ml]        = acc0[r];
        Csc[(size_t)(32 + l31) * 130 + wid * 32 + ml] = acc1[r];
    }
    __syncthreads();
    #pragma unroll
    for (int it = 0; it < 16; ++it) {
        int flat = it * 256 + tid;
        int o = flat >> 6, hh = (flat >> 5) & 1, fc = flat & 31;
        if (fc < 31) {
            float2 v = *(float2*)&Csc[(size_t)o * 130 + hh * 64 + fc * 2];
            *(float2*)&out[((size_t)(bb * OD + o) * HO + h0 + hh) * WO + fc * 2] = v;
        }
    }
}

// =================== fallback path (small ws): round-2 kernels ===================
#define NCHUNK 36
#define FW 68
__global__ __launch_bounds__(256) void kan_prep(const float* __restrict__ coef,
                                                const float* __restrict__ sbase,
                                                const float* __restrict__ ssp,
                                                ushort* __restrict__ wp) {
    int idx = blockIdx.x * 256 + threadIdx.x;
    if (idx >= ND * OD * 8) return;
    int n = idx & 7, o = (idx >> 3) & 63, d = idx >> 9;
    float v = (n < 6) ? coef[(d * OD + o) * 6 + n] * ssp[d * OD + o] : sbase[d * OD + o];
    wp[idx] = f2bf(v);
}

__global__ __launch_bounds__(128) void kan_mfma(const float* __restrict__ x,
                                                const ushort* __restrict__ wp,
                                                float* __restrict__ out) {
    __shared__ uint4 feat[Cc * 4 * FW];
    const int rp = blockIdx.x, b = blockIdx.y, tid = threadIdx.x;
    const int wid = tid >> 6, lane = tid & 63, l15 = lane & 15, ks = lane >> 4;
    const int hrow0 = rp * 2;
    for (int i = tid; i < Cc * 4 * FW; i += 128) {
        int wl = i % FW, cr = i / FW, r = cr & 3, c = cr >> 2;
        int col = wl < Ww ? wl : Ww - 1;
        feat[i] = feat_pack(x[((b * Cc + c) * Hh + hrow0 + r) * Ww + col]);
    }
    __syncthreads();
    f32x4 acc[4][4];
    #pragma unroll
    for (int rt = 0; rt < 4; ++rt)
        #pragma unroll
        for (int ct = 0; ct < 4; ++ct) acc[rt][ct] = (f32x4){0.f, 0.f, 0.f, 0.f};
    auto loadA = [&](int chunk, short8* A) {
        int d = chunk * 4 + ks;
        int c = (d * 57) >> 9;
        int rem = d - c * 9;
        int di = (rem * 11) >> 5;
        int dj = rem - di * 3;
        const short8* ap = (const short8*)&feat[(c * 4 + wid + di) * FW + l15 + dj];
        A[0] = ap[0]; A[1] = ap[16]; A[2] = ap[32]; A[3] = ap[48];
    };
    auto loadB = [&](int chunk, short8* Bf) {
        int d = chunk * 4 + ks;
        const short8* bp = (const short8*)wp + (d * 64 + l15);
        Bf[0] = bp[0]; Bf[1] = bp[16]; Bf[2] = bp[32]; Bf[3] = bp[48];
    };
    short8 A0[4], B0[4], A1[4], B1[4];
    loadA(0, A0); loadB(0, B0);
    for (int cb = 0; cb < NCHUNK; cb += 2) {
        loadA(cb + 1, A1); loadB(cb + 1, B1);
        #pragma unroll
        for (int rt = 0; rt < 4; ++rt)
            #pragma unroll
            for (int ct = 0; ct < 4; ++ct)
                acc[rt][ct] = __builtin_amdgcn_mfma_f32_16x16x32_bf16(A0[rt], B0[ct], acc[rt][ct], 0, 0, 0);
        if (cb + 2 < NCHUNK) { loadA(cb + 2, A0); loadB(cb + 2, B0); }
        #pragma unroll
        for (int rt = 0; rt < 4; ++rt)
            #pragma unroll
            for (int ct = 0; ct < 4; ++ct)
                acc[rt][ct] = __builtin_amdgcn_mfma_f32_16x16x32_bf16(A1[rt], B1[ct], acc[rt][ct], 0, 0, 0);
    }
    __syncthreads();
    float* sC = ((float*)feat) + wid * (OD * FW);
    #pragma unroll
    for (int rt = 0; rt < 4; ++rt)
        #pragma unroll
        for (int ct = 0; ct < 4; ++ct)
            *(f32x4*)&sC[(ct * 16 + l15) * FW + rt * 16 + ks * 4] = acc[rt][ct];
    const int orow = hrow0 + wid;
    for (int j = 0; j < OD; ++j) {
        float v = sC[j * FW + lane];
        if (lane < WO) out[((b * OD + j) * HO + orow) * WO + lane] = v;
    }
}

extern "C" void kernel_launch(void* const* d_in, const int* in_sizes, int n_in,
                              void* d_out, int out_size, void* d_ws, size_t ws_size,
                              hipStream_t stream) {
    (void)in_sizes; (void)n_in; (void)out_size;
    const float* x     = (const float*)d_in[0];
    const float* coef  = (const float*)d_in[1];
    const float* sbase = (const float*)d_in[2];
    const float* ssp   = (const float*)d_in[3];
    float* out = (float*)d_out;

    const size_t wpb_bytes = (size_t)KC * 512 * 16;              // 147,456
    const size_t fg_bytes  = (size_t)Bsz * Cc * Hh * Ww * 16;    // 33,554,432
    const size_t need = wpb_bytes + fg_bytes + 4096;             // +guard for 16B overreach

    if (ws_size >= need) {
        uint4* wpb = (uint4*)d_ws;
        uint4* fg  = (uint4*)((char*)d_ws + wpb_bytes);
        kan_feat<<<1024, 256, 0, stream>>>(x, fg);
        kan_prep3<<<36, 256, 0, stream>>>(coef, sbase, ssp, (ushort*)wpb);
        dim3 grid(31, Bsz);
        kan_gemm2<<<grid, 256, 0, stream>>>(fg, wpb, out);
    } else if (ws_size >= (size_t)ND * OD * 8 * 2) {
        ushort* wp = (ushort*)d_ws;
        kan_prep<<<(ND * OD * 8 + 255) / 256, 256, 0, stream>>>(coef, sbase, ssp, wp);
        dim3 grid(HO / 2, Bsz);
        kan_mfma<<<grid, 128, 0, stream>>>(x, wp, out);
    }
}